// Round 1
// 2040.749 us; speedup vs baseline: 1.5281x; 1.5281x over previous
//
#include <hip/hip_runtime.h>

// ---- problem constants ----
#define S_    1024
#define D_    768
#define H_    12
#define HD_   64
#define L_    6
#define B_    2
#define V_    32000
#define NTOK  2048          // B_*S_
#define DD    (D_ * D_)     // 589824
#define D4D   (D_ * 4 * D_) // 2359296

typedef __bf16 bf16_t;
typedef __bf16 bf16x8 __attribute__((ext_vector_type(8)));
typedef float  f32x4  __attribute__((ext_vector_type(4)));

// async global->LDS, 16B per lane; lds ptr must be wave-uniform base (lane*16 added by HW)
__device__ __forceinline__ void async_ld16(const bf16_t* g, bf16_t* l) {
  __builtin_amdgcn_global_load_lds((__attribute__((address_space(1))) void*)(g),
                                   (__attribute__((address_space(3))) void*)(l),
                                   16, 0, 0);
}

__device__ __forceinline__ float wave_sum(float v) {
#pragma unroll
  for (int off = 32; off; off >>= 1) v += __shfl_xor(v, off);
  return v;
}
__device__ __forceinline__ float wave_max(float v) {
#pragma unroll
  for (int off = 32; off; off >>= 1) v = fmaxf(v, __shfl_xor(v, off));
  return v;
}

// dtype-flexible scalar load: inputs may be bf16 or fp32 (runtime-sniffed)
__device__ __forceinline__ float ldv(const void* p, size_t i, bool f32) {
  return f32 ? ((const float*)p)[i] : (float)((const bf16_t*)p)[i];
}

// ======================= dtype sniff =======================
// Interpret first 256 elems of tok_emb as bf16. True bf16 data ~N(0,0.02) never
// exceeds 1e6; fp32 data read as bf16 has random-exponent low halves -> trips it
// with prob 1 - ~1e-31. Deterministic per input => graph-safe.
__global__ void k_sniff(const void* tok, int* flag) {
  const bf16_t* p = (const bf16_t*)tok;
  float mx = 0.f;
  for (int i = threadIdx.x; i < 256; i += 64) {
    float v = fabsf((float)p[i]);
    mx = fmaxf(mx, v);
  }
  mx = wave_max(mx);
  if (threadIdx.x == 0) *flag = (mx > 1.0e6f) ? 1 : 0;
}

// ======================= bias canonicalization (-> bf16) =======================
__global__ __launch_bounds__(256) void k_cvt_bias(const int* flag, bf16_t* canon,
    const void* bo, const void* b1, const void* b2, const void* l1g, const void* l1b,
    const void* l2g, const void* l2b, const void* lfg, const void* lfb, const void* bout) {
  const bool f32 = (*flag != 0);
  const void* src; int off, n;
  switch (blockIdx.y) {
    case 0: src = bo;  off = 0;     n = 4608;  break;
    case 1: src = b1;  off = 4608;  n = 18432; break;
    case 2: src = b2;  off = 23040; n = 4608;  break;
    case 3: src = l1g; off = 27648; n = 4608;  break;
    case 4: src = l1b; off = 32256; n = 4608;  break;
    case 5: src = l2g; off = 36864; n = 4608;  break;
    case 6: src = l2b; off = 41472; n = 4608;  break;
    case 7: src = lfg; off = 46080; n = 768;   break;
    case 8: src = lfb; off = 46848; n = 768;   break;
    default: src = bout; off = 47616; n = 32000; break;
  }
  const int i = blockIdx.x * 256 + threadIdx.x;
  if (i < n) canon[off + i] = (bf16_t)ldv(src, (size_t)i, f32);
}

// ======================= GEMM: C[M,N] = A[M,K] @ B[K,N], B given transposed (BT[N,K]) ===================
// 128x128 tile, BK=32, 256 threads (4 waves, each 64x64 = 4x4 mfma_16x16x32_bf16)
enum { E_STORE = 0, E_BIAS_OUT = 1, E_BIAS_RELU = 2, E_BIAS_RES = 3 };

template <int EPI>
__device__ __forceinline__ void gemm_core(const bf16_t* __restrict__ A,
                                          const bf16_t* __restrict__ BT,
                                          const bf16_t* __restrict__ bias,
                                          void* __restrict__ Cb,
                                          float* __restrict__ resid,
                                          const int* f32out,
                                          int M, int N, int K) {
  __shared__ bf16_t sA[128 * 32];
  __shared__ bf16_t sB[128 * 32];
  const int tid  = threadIdx.x;
  const int wave = tid >> 6, lane = tid & 63;
  const int quad = lane >> 4, l16 = lane & 15;
  const int m0 = blockIdx.y * 128, n0 = blockIdx.x * 128;
  const int wm = (wave >> 1) * 64, wn = (wave & 1) * 64;

  const f32x4 zero = {0.f, 0.f, 0.f, 0.f};
  f32x4 acc[4][4];
#pragma unroll
  for (int i = 0; i < 4; i++)
#pragma unroll
    for (int j = 0; j < 4; j++) acc[i][j] = zero;

  // staging: wave w covers rows [w*32, w*32+32) of the 128-row tile; 2 async instrs per matrix
  const bf16_t* gA = A  + (size_t)(m0 + wave * 32 + (lane >> 2)) * K + (lane & 3) * 8;
  const bf16_t* gB = BT + (size_t)(n0 + wave * 32 + (lane >> 2)) * K + (lane & 3) * 8;
  bf16_t* lA = sA + wave * 1024;   // wave-uniform base
  bf16_t* lB = sB + wave * 1024;
  const size_t k16 = (size_t)16 * K;

  for (int k0 = 0; k0 < K; k0 += 32) {
    async_ld16(gA, lA);
    async_ld16(gA + k16, lA + 512);
    async_ld16(gB, lB);
    async_ld16(gB + k16, lB + 512);
    gA += 32; gB += 32;
    __syncthreads();   // compiler drains vmcnt(0) before barrier: LDS tiles valid

    bf16x8 af[4], bfr[4];
#pragma unroll
    for (int i = 0; i < 4; i++) {
      af[i]  = *(const bf16x8*)(sA + (wm + i * 16 + l16) * 32 + quad * 8);
      bfr[i] = *(const bf16x8*)(sB + (wn + i * 16 + l16) * 32 + quad * 8);
    }
#pragma unroll
    for (int mi = 0; mi < 4; mi++)
#pragma unroll
      for (int ni = 0; ni < 4; ni++)
        acc[mi][ni] = __builtin_amdgcn_mfma_f32_16x16x32_bf16(af[mi], bfr[ni], acc[mi][ni], 0, 0, 0);
    __syncthreads();   // protect LDS before next iteration's staging
  }

  const bool f32o = (EPI == E_BIAS_OUT) && (*f32out != 0);
  // epilogue: C/D layout col=lane&15, row=quad*4+reg (m89-verified)
#pragma unroll
  for (int mi = 0; mi < 4; mi++) {
#pragma unroll
    for (int ni = 0; ni < 4; ni++) {
      const int r0 = m0 + wm + mi * 16 + quad * 4;
      const int c  = n0 + wn + ni * 16 + l16;
      float bv = 0.f;
      if (EPI != E_STORE) bv = (float)bias[c];
#pragma unroll
      for (int r = 0; r < 4; r++) {
        float val = acc[mi][ni][r] + bv;
        if (EPI == E_BIAS_RELU) val = fmaxf(val, 0.f);
        const size_t idx = (size_t)(r0 + r) * N + c;
        if (EPI == E_BIAS_RES) {
          resid[idx] += val;
        } else if (EPI == E_BIAS_OUT) {
          if (f32o) ((float*)Cb)[idx] = val;
          else      ((bf16_t*)Cb)[idx] = (bf16_t)val;
        } else {
          ((bf16_t*)Cb)[idx] = (bf16_t)val;
        }
      }
    }
  }
}

__global__ __launch_bounds__(256) void k_gemm_qkv(const bf16_t* __restrict__ A,
                                                  const bf16_t* __restrict__ BT0,
                                                  const bf16_t* __restrict__ BT1,
                                                  const bf16_t* __restrict__ BT2,
                                                  bf16_t* __restrict__ o0,
                                                  bf16_t* __restrict__ o1,
                                                  bf16_t* __restrict__ o2,
                                                  int M, int N, int K) {
  const bf16_t* BT = (blockIdx.z == 0) ? BT0 : (blockIdx.z == 1) ? BT1 : BT2;
  bf16_t* o = (blockIdx.z == 0) ? o0 : (blockIdx.z == 1) ? o1 : o2;
  gemm_core<E_STORE>(A, BT, nullptr, o, nullptr, nullptr, M, N, K);
}
__global__ __launch_bounds__(256) void k_gemm_bias_relu(const bf16_t* __restrict__ A, const bf16_t* __restrict__ BT,
                                                        const bf16_t* __restrict__ bias, bf16_t* __restrict__ C,
                                                        int M, int N, int K) {
  gemm_core<E_BIAS_RELU>(A, BT, bias, C, nullptr, nullptr, M, N, K);
}
__global__ __launch_bounds__(256) void k_gemm_bias_res(const bf16_t* __restrict__ A, const bf16_t* __restrict__ BT,
                                                       const bf16_t* __restrict__ bias, float* __restrict__ resid,
                                                       int M, int N, int K) {
  gemm_core<E_BIAS_RES>(A, BT, bias, nullptr, resid, nullptr, M, N, K);
}
__global__ __launch_bounds__(256) void k_gemm_out(const bf16_t* __restrict__ A, const bf16_t* __restrict__ BT,
                                                  const bf16_t* __restrict__ bias, void* __restrict__ C,
                                                  const int* flag, int M, int N, int K) {
  gemm_core<E_BIAS_OUT>(A, BT, bias, C, nullptr, flag, M, N, K);
}

// ======================= weight transpose into rotating slot: out[N,K] = in[K,N] =======================
__global__ __launch_bounds__(256) void k_t(const int* flag, const void* __restrict__ in, size_t eoff,
                                           bf16_t* __restrict__ out, int K, int N) {
  __shared__ bf16_t t[32][33];
  const bool f32 = (*flag != 0);
  const int n0 = blockIdx.x * 32, k0 = blockIdx.y * 32;
  const int tx = threadIdx.x, ty = threadIdx.y;  // (32,8)
#pragma unroll
  for (int i = 0; i < 4; i++)
    t[ty + 8 * i][tx] = (bf16_t)ldv(in, eoff + (size_t)(k0 + ty + 8 * i) * N + n0 + tx, f32);
  __syncthreads();
#pragma unroll
  for (int i = 0; i < 4; i++)
    out[(size_t)(n0 + ty + 8 * i) * K + k0 + tx] = t[tx][ty + 8 * i];
}

// q/k/v weights for one layer in one launch (z selects matrix, writes slot + z*DD)
__global__ __launch_bounds__(256) void k_t_qkv(const int* flag, const void* __restrict__ Wq,
                                               const void* __restrict__ Wk, const void* __restrict__ Wv,
                                               size_t eoff, bf16_t* __restrict__ out) {
  __shared__ bf16_t t[32][33];
  const bool f32 = (*flag != 0);
  const void* in = (blockIdx.z == 0) ? Wq : (blockIdx.z == 1) ? Wk : Wv;
  bf16_t* o = out + (size_t)blockIdx.z * DD;
  const int n0 = blockIdx.x * 32, k0 = blockIdx.y * 32;
  const int tx = threadIdx.x, ty = threadIdx.y;
#pragma unroll
  for (int i = 0; i < 4; i++)
    t[ty + 8 * i][tx] = (bf16_t)ldv(in, eoff + (size_t)(k0 + ty + 8 * i) * D_ + n0 + tx, f32);
  __syncthreads();
#pragma unroll
  for (int i = 0; i < 4; i++)
    o[(size_t)(n0 + ty + 8 * i) * D_ + k0 + tx] = t[tx][ty + 8 * i];
}

// ======================= V transpose: vt[b*768 + d][s] = v[b*1024 + s][d] (bf16 -> bf16) ==============
__global__ __launch_bounds__(256) void k_vt(const bf16_t* __restrict__ v, bf16_t* __restrict__ vt) {
  __shared__ bf16_t t[32][33];
  const int b = blockIdx.z;
  const int n0 = blockIdx.x * 32, s0 = blockIdx.y * 32;
  const int tx = threadIdx.x, ty = threadIdx.y;  // (32,8)
#pragma unroll
  for (int i = 0; i < 4; i++)
    t[ty + 8 * i][tx] = v[(size_t)(b * S_ + s0 + ty + 8 * i) * D_ + n0 + tx];
  __syncthreads();
#pragma unroll
  for (int i = 0; i < 4; i++)
    vt[(size_t)(b * D_ + n0 + ty + 8 * i) * S_ + s0 + tx] = t[tx][ty + 8 * i];
}

// ======================= embedding (fp32 residual) =======================
__global__ __launch_bounds__(256) void k_embed(const int* flag, const int* __restrict__ cidx,
                                               const void* __restrict__ tok, const void* __restrict__ pos,
                                               float* __restrict__ x) {
  const bool f32 = (*flag != 0);
  const int t = blockIdx.x;
  const int id = cidx[t];
  const int s = t & (S_ - 1);
  for (int d = threadIdx.x; d < D_; d += 256)
    x[(size_t)t * D_ + d] = ldv(tok, (size_t)id * D_ + d, f32) + ldv(pos, (size_t)s * D_ + d, f32);
}

// ======================= layernorm: fp32 in -> bf16 out =======================
__global__ __launch_bounds__(256) void k_ln(const float* __restrict__ x, const bf16_t* __restrict__ g,
                                            const bf16_t* __restrict__ bta, bf16_t* __restrict__ out) {
  __shared__ float red[4];
  const int t = blockIdx.x, tid = threadIdx.x;
  const int wave = tid >> 6, lane = tid & 63;
  const float* xr = x + (size_t)t * D_;
  const float v0 = xr[tid], v1 = xr[tid + 256], v2 = xr[tid + 512];
  float s = wave_sum(v0 + v1 + v2);
  if (lane == 0) red[wave] = s;
  __syncthreads();
  const float mean = (red[0] + red[1] + red[2] + red[3]) * (1.f / 768.f);
  const float d0 = v0 - mean, d1 = v1 - mean, d2 = v2 - mean;
  float vs = wave_sum(d0 * d0 + d1 * d1 + d2 * d2);
  __syncthreads();
  if (lane == 0) red[wave] = vs;
  __syncthreads();
  const float inv = rsqrtf((red[0] + red[1] + red[2] + red[3]) * (1.f / 768.f) + 1e-5f);
  bf16_t* o = out + (size_t)t * D_;
  o[tid]       = (bf16_t)(d0 * inv * (float)g[tid]       + (float)bta[tid]);
  o[tid + 256] = (bf16_t)(d1 * inv * (float)g[tid + 256] + (float)bta[tid + 256]);
  o[tid + 512] = (bf16_t)(d2 * inv * (float)g[tid + 512] + (float)bta[tid + 512]);
}

// ======================= flash attention: 1 wave = 16 queries, MFMA QK^T and P@V ======================
// Online softmax per query row; P bounced bf16 through a 1.25KB wave-private LDS buffer
// (row stride 40 bf16 = 80B keeps ds_read_b128 A-fragment reads 16B-aligned & conflict-free).
// V is consumed from the pre-transposed vt[b*768+d][s] so PV B-fragments are contiguous 16B loads.
__global__ __launch_bounds__(64) void k_fattn(const bf16_t* __restrict__ q,
                                              const bf16_t* __restrict__ k,
                                              const bf16_t* __restrict__ vt,
                                              bf16_t* __restrict__ ctx) {
  __shared__ bf16_t sP[16 * 40];
  const int lane = threadIdx.x;
  const int quad = lane >> 4, l16 = lane & 15;
  const int q0 = blockIdx.x << 4, h = blockIdx.y, b = blockIdx.z;
  const size_t hoff = (size_t)h * HD_;

  // Q fragments (A-operand: m=l16=query, k=quad*8+j over d); head dim 64 -> two k=32 fragments
  const bf16_t* qp = q + (size_t)(b * S_ + q0 + l16) * D_ + hoff + quad * 8;
  const bf16x8 af0 = *(const bf16x8*)qp;
  const bf16x8 af1 = *(const bf16x8*)(qp + 32);

  const f32x4 zero = {0.f, 0.f, 0.f, 0.f};
  f32x4 o_acc[4];           // d column tiles ct=0..3; rows quad*4+r = query (C-layout)
  float m_run[4], l_run[4]; // per query row r
#pragma unroll
  for (int ct = 0; ct < 4; ++ct) o_acc[ct] = zero;
#pragma unroll
  for (int r = 0; r < 4; ++r) { m_run[r] = -1e30f; l_run[r] = 0.f; }

  const int nt = ((q0 + 15) >> 5) + 1;   // 32-key tiles in causal range
  const bf16_t* kbase = k + (size_t)(b * S_ + l16) * D_ + hoff + quad * 8;
  const size_t kst = (size_t)16 * D_;
  // prologue: K fragments for tile 0 (B-operand: n=l16=key, k=quad*8+j over d)
  bf16x8 kf0 = *(const bf16x8*)(kbase);
  bf16x8 kf1 = *(const bf16x8*)(kbase + 32);
  bf16x8 kf2 = *(const bf16x8*)(kbase + kst);
  bf16x8 kf3 = *(const bf16x8*)(kbase + kst + 32);

  const bf16_t* vbase = vt + (size_t)(b * D_ + hoff + l16) * S_ + quad * 8;

  for (int kt = 0; kt < nt; ++kt) {
    const int k0 = kt << 5;
    // issue V loads early (consumed after softmax ~150cy later)
    const bf16_t* vrow = vbase + k0;
    const bf16x8 vb0 = *(const bf16x8*)(vrow);
    const bf16x8 vb1 = *(const bf16x8*)(vrow + 16 * S_);
    const bf16x8 vb2 = *(const bf16x8*)(vrow + 32 * S_);
    const bf16x8 vb3 = *(const bf16x8*)(vrow + 48 * S_);

    // QK^T: scores for 16 queries x 32 keys (two 16-key column tiles)
    f32x4 d0 = zero, d1 = zero;
    d0 = __builtin_amdgcn_mfma_f32_16x16x32_bf16(af0, kf0, d0, 0, 0, 0);
    d0 = __builtin_amdgcn_mfma_f32_16x16x32_bf16(af1, kf1, d0, 0, 0, 0);
    d1 = __builtin_amdgcn_mfma_f32_16x16x32_bf16(af0, kf2, d1, 0, 0, 0);
    d1 = __builtin_amdgcn_mfma_f32_16x16x32_bf16(af1, kf3, d1, 0, 0, 0);

    // prefetch next K tile (hidden under softmax + PV)
    if (kt + 1 < nt) {
      const bf16_t* kpn = kbase + (size_t)(k0 + 32) * D_;
      kf0 = *(const bf16x8*)(kpn);
      kf1 = *(const bf16x8*)(kpn + 32);
      kf2 = *(const bf16x8*)(kpn + kst);
      kf3 = *(const bf16x8*)(kpn + kst + 32);
    }

    // online softmax: C-layout row = quad*4+r (query), col = l16 / 16+l16 (key)
    const bool msk = (kt == nt - 1);
    float al[4];
#pragma unroll
    for (int r = 0; r < 4; ++r) {
      float s0 = d0[r] * 0.125f;   // 1/sqrt(64)
      float s1 = d1[r] * 0.125f;
      if (msk) {
        const int row = q0 + quad * 4 + r;
        if (k0 + l16      > row) s0 = -1e30f;
        if (k0 + 16 + l16 > row) s1 = -1e30f;
      }
      float mt = fmaxf(s0, s1);
      mt = fmaxf(mt, __shfl_xor(mt, 1));
      mt = fmaxf(mt, __shfl_xor(mt, 2));
      mt = fmaxf(mt, __shfl_xor(mt, 4));
      mt = fmaxf(mt, __shfl_xor(mt, 8));
      const float mn = fmaxf(m_run[r], mt);
      const float a  = __expf(m_run[r] - mn);
      m_run[r] = mn;
      const float p0 = __expf(s0 - mn);
      const float p1 = __expf(s1 - mn);
      float ps = p0 + p1;
      ps += __shfl_xor(ps, 1);
      ps += __shfl_xor(ps, 2);
      ps += __shfl_xor(ps, 4);
      ps += __shfl_xor(ps, 8);
      l_run[r] = l_run[r] * a + ps;
      al[r] = a;
      sP[(quad * 4 + r) * 40 + l16]      = (bf16_t)p0;
      sP[(quad * 4 + r) * 40 + 16 + l16] = (bf16_t)p1;
    }
    // rescale accumulator by alpha (per query row)
#pragma unroll
    for (int ct = 0; ct < 4; ++ct) {
      o_acc[ct][0] *= al[0]; o_acc[ct][1] *= al[1];
      o_acc[ct][2] *= al[2]; o_acc[ct][3] *= al[3];
    }
    // P as A-fragment (compiler inserts lgkmcnt wait for the LDS RAW)
    const bf16x8 pa = *(const bf16x8*)(sP + l16 * 40 + quad * 8);
    o_acc[0] = __builtin_amdgcn_mfma_f32_16x16x32_bf16(pa, vb0, o_acc[0], 0, 0, 0);
    o_acc[1] = __builtin_amdgcn_mfma_f32_16x16x32_bf16(pa, vb1, o_acc[1], 0, 0, 0);
    o_acc[2] = __builtin_amdgcn_mfma_f32_16x16x32_bf16(pa, vb2, o_acc[2], 0, 0, 0);
    o_acc[3] = __builtin_amdgcn_mfma_f32_16x16x32_bf16(pa, vb3, o_acc[3], 0, 0, 0);
  }

  float inv[4];
#pragma unroll
  for (int r = 0; r < 4; ++r) inv[r] = 1.f / l_run[r];
  bf16_t* cp = ctx + (size_t)(b * S_ + q0 + quad * 4) * D_ + hoff + l16;
#pragma unroll
  for (int ct = 0; ct < 4; ++ct)
#pragma unroll
    for (int r = 0; r < 4; ++r)
      cp[(size_t)r * D_ + ct * 16] = (bf16_t)(o_acc[ct][r] * inv[r]);
}

// ======================= host =======================
extern "C" void kernel_launch(void* const* d_in, const int* in_sizes, int n_in,
                              void* d_out, int out_size, void* d_ws, size_t ws_size,
                              hipStream_t stream) {
  (void)in_sizes; (void)n_in; (void)out_size; (void)ws_size;
  const int* cidx = (const int*)d_in[0];
  const void* tok  = d_in[1];
  const void* pos  = d_in[2];
  const void* Wq   = d_in[3];
  const void* Wk   = d_in[4];
  const void* Wv   = d_in[5];
  const void* Wo   = d_in[6];
  const void* bo   = d_in[7];
  const void* ln1g = d_in[8];
  const void* ln1b = d_in[9];
  const void* W1   = d_in[10];
  const void* b1   = d_in[11];
  const void* W2   = d_in[12];
  const void* b2   = d_in[13];
  const void* ln2g = d_in[14];
  const void* ln2b = d_in[15];
  const void* lnfg = d_in[16];
  const void* lnfb = d_in[17];
  const void* Wout = d_in[18];
  const void* bout = d_in[19];

  // ---- workspace carve, total ~84 MB (rotating weight slot, reused per GEMM) ----
  char* p = (char*)d_ws;
  int*    flag  = (int*)p;
  bf16_t* canon = (bf16_t*)(p + 256);            // 79,616 bf16 elems (~156 KB)
  char*   q     = p + 256 + 163840;              // canon region reserved 160 KB
  float*  x     = (float*)q;  q += (size_t)NTOK * D_ * 4;       // 6.29 MB
  bf16_t* h     = (bf16_t*)q; q += (size_t)NTOK * D_ * 2;       // 3.15 MB
  bf16_t* qb    = (bf16_t*)q; q += (size_t)NTOK * D_ * 2;
  bf16_t* kbuf  = (bf16_t*)q; q += (size_t)NTOK * D_ * 2;
  bf16_t* vbuf  = (bf16_t*)q; q += (size_t)NTOK * D_ * 2;
  bf16_t* cbuf  = (bf16_t*)q; q += (size_t)NTOK * D_ * 2;
  bf16_t* mid   = (bf16_t*)q; q += (size_t)NTOK * 4 * D_ * 2;   // 12.6 MB
  bf16_t* slot  = (bf16_t*)q; q += (size_t)D_ * V_ * 2;         // 49.2 MB (max weight = WoutT)
  // vt (3.1 MB) aliases mid: vt is live only between k_gemm_qkv and k_fattn,
  // mid is written (FFN1) strictly after k_fattn completes on the serial stream.
  bf16_t* vt = mid;

  // canon sub-pointers (element offsets fixed to match k_cvt_bias)
  bf16_t* c_bo  = canon + 0;
  bf16_t* c_b1  = canon + 4608;
  bf16_t* c_b2  = canon + 23040;
  bf16_t* c_l1g = canon + 27648;
  bf16_t* c_l1b = canon + 32256;
  bf16_t* c_l2g = canon + 36864;
  bf16_t* c_l2b = canon + 41472;
  bf16_t* c_lfg = canon + 46080;
  bf16_t* c_lfb = canon + 46848;
  bf16_t* c_bout= canon + 47616;

  const dim3 tb(32, 8);
  k_sniff<<<1, 64, 0, stream>>>(tok, flag);
  k_cvt_bias<<<dim3(125, 10), 256, 0, stream>>>(flag, canon, bo, b1, b2, ln1g, ln1b,
                                                ln2g, ln2b, lnfg, lnfb, bout);
  k_embed<<<NTOK, 256, 0, stream>>>(flag, cidx, tok, pos, x);

  const dim3 gD(D_ / 128, NTOK / 128);        // N=768
  const dim3 gF(4 * D_ / 128, NTOK / 128);    // N=3072
  for (int l = 0; l < L_; ++l) {
    const size_t wo = (size_t)l * DD;
    const size_t wf = (size_t)l * D4D;
    k_ln<<<NTOK, 256, 0, stream>>>(x, c_l1g + l * D_, c_l1b + l * D_, h);
    k_t_qkv<<<dim3(24, 24, 3), tb, 0, stream>>>(flag, Wq, Wk, Wv, wo, slot);
    k_gemm_qkv<<<dim3(D_ / 128, NTOK / 128, 3), 256, 0, stream>>>(
        h, slot, slot + DD, slot + 2 * DD, qb, kbuf, vbuf, NTOK, D_, D_);
    k_vt<<<dim3(24, 32, 2), tb, 0, stream>>>(vbuf, vt);
    k_fattn<<<dim3(S_ / 16, H_, B_), 64, 0, stream>>>(qb, kbuf, vt, cbuf);
    k_t<<<dim3(24, 24), tb, 0, stream>>>(flag, Wo, wo, slot, D_, D_);
    k_gemm_bias_res<<<gD, 256, 0, stream>>>(cbuf, slot, c_bo + l * D_, x, NTOK, D_, D_);
    k_ln<<<NTOK, 256, 0, stream>>>(x, c_l2g + l * D_, c_l2b + l * D_, h);
    k_t<<<dim3(96, 24), tb, 0, stream>>>(flag, W1, wf, slot, D_, 4 * D_);
    k_gemm_bias_relu<<<gF, 256, 0, stream>>>(h, slot, c_b1 + l * 4 * D_, mid, NTOK, 4 * D_, D_);
    k_t<<<dim3(24, 96), tb, 0, stream>>>(flag, W2, wf, slot, 4 * D_, D_);
    k_gemm_bias_res<<<gD, 256, 0, stream>>>(mid, slot, c_b2 + l * D_, x, NTOK, D_, 4 * D_);
  }
  k_ln<<<NTOK, 256, 0, stream>>>(x, c_lfg, c_lfb, h);
  k_t<<<dim3(1000, 24), tb, 0, stream>>>(flag, Wout, 0, slot, D_, V_);
  k_gemm_out<<<dim3(V_ / 128, NTOK / 128), 256, 0, stream>>>(h, slot, c_bout, d_out, flag,
                                                             NTOK, V_, D_);
}

// Round 2
// 1746.690 us; speedup vs baseline: 1.7854x; 1.1684x over previous
//
#include <hip/hip_runtime.h>

// ---- problem constants ----
#define S_    1024
#define D_    768
#define H_    12
#define HD_   64
#define L_    6
#define B_    2
#define V_    32000
#define NTOK  2048          // B_*S_
#define DD    (D_ * D_)     // 589824
#define D4D   (D_ * 4 * D_) // 2359296

typedef __bf16 bf16_t;
typedef __bf16 bf16x8 __attribute__((ext_vector_type(8)));
typedef float  f32x4  __attribute__((ext_vector_type(4)));

// async global->LDS, 16B per lane; lds ptr must be wave-uniform base (lane*16 added by HW)
__device__ __forceinline__ void async_ld16(const bf16_t* g, bf16_t* l) {
  __builtin_amdgcn_global_load_lds((__attribute__((address_space(1))) void*)(g),
                                   (__attribute__((address_space(3))) void*)(l),
                                   16, 0, 0);
}

__device__ __forceinline__ float wave_sum(float v) {
#pragma unroll
  for (int off = 32; off; off >>= 1) v += __shfl_xor(v, off);
  return v;
}
__device__ __forceinline__ float wave_max(float v) {
#pragma unroll
  for (int off = 32; off; off >>= 1) v = fmaxf(v, __shfl_xor(v, off));
  return v;
}

// dtype-flexible scalar load: inputs may be bf16 or fp32 (runtime-sniffed)
__device__ __forceinline__ float ldv(const void* p, size_t i, bool f32) {
  return f32 ? ((const float*)p)[i] : (float)((const bf16_t*)p)[i];
}

// ======================= dtype sniff =======================
__global__ void k_sniff(const void* tok, int* flag) {
  const bf16_t* p = (const bf16_t*)tok;
  float mx = 0.f;
  for (int i = threadIdx.x; i < 256; i += 64) {
    float v = fabsf((float)p[i]);
    mx = fmaxf(mx, v);
  }
  mx = wave_max(mx);
  if (threadIdx.x == 0) *flag = (mx > 1.0e6f) ? 1 : 0;
}

// ======================= bias canonicalization (-> bf16) =======================
__global__ __launch_bounds__(256) void k_cvt_bias(const int* flag, bf16_t* canon,
    const void* bo, const void* b1, const void* b2, const void* l1g, const void* l1b,
    const void* l2g, const void* l2b, const void* lfg, const void* lfb, const void* bout) {
  const bool f32 = (*flag != 0);
  const void* src; int off, n;
  switch (blockIdx.y) {
    case 0: src = bo;  off = 0;     n = 4608;  break;
    case 1: src = b1;  off = 4608;  n = 18432; break;
    case 2: src = b2;  off = 23040; n = 4608;  break;
    case 3: src = l1g; off = 27648; n = 4608;  break;
    case 4: src = l1b; off = 32256; n = 4608;  break;
    case 5: src = l2g; off = 36864; n = 4608;  break;
    case 6: src = l2b; off = 41472; n = 4608;  break;
    case 7: src = lfg; off = 46080; n = 768;   break;
    case 8: src = lfb; off = 46848; n = 768;   break;
    default: src = bout; off = 47616; n = 32000; break;
  }
  const int i = blockIdx.x * 256 + threadIdx.x;
  if (i < n) canon[off + i] = (bf16_t)ldv(src, (size_t)i, f32);
}

// ======================= GEMM core: C[M,N] = A[M,K] @ BT[N,K]^T =======================
// 128x128 tile, BK=32, 256 threads (4 waves, each 64x64 = 4x4 mfma_16x16x32_bf16).
// Tile coords (m0,n0) and K-range [kb,ke) passed in (enables swizzle + split-K).
enum { E_STORE = 0, E_BIAS_OUT = 1, E_BIAS_RELU = 2, E_BIAS_RES_AT = 3 };

template <int EPI>
__device__ __forceinline__ void gemm_core(const bf16_t* __restrict__ A,
                                          const bf16_t* __restrict__ BT,
                                          const bf16_t* __restrict__ bias,
                                          void* __restrict__ Cb,
                                          float* __restrict__ resid,
                                          const int* f32out,
                                          int M, int N, int K,
                                          int m0, int n0, int kb, int ke) {
  __shared__ bf16_t sA[128 * 32];
  __shared__ bf16_t sB[128 * 32];
  const int tid  = threadIdx.x;
  const int wave = tid >> 6, lane = tid & 63;
  const int quad = lane >> 4, l16 = lane & 15;
  const int wm = (wave >> 1) * 64, wn = (wave & 1) * 64;

  const f32x4 zero = {0.f, 0.f, 0.f, 0.f};
  f32x4 acc[4][4];
#pragma unroll
  for (int i = 0; i < 4; i++)
#pragma unroll
    for (int j = 0; j < 4; j++) acc[i][j] = zero;

  // staging: wave w covers rows [w*32, w*32+32) of the 128-row tile; 2 async instrs per matrix
  const bf16_t* gA = A  + (size_t)(m0 + wave * 32 + (lane >> 2)) * K + kb + (lane & 3) * 8;
  const bf16_t* gB = BT + (size_t)(n0 + wave * 32 + (lane >> 2)) * K + kb + (lane & 3) * 8;
  bf16_t* lA = sA + wave * 1024;   // wave-uniform base
  bf16_t* lB = sB + wave * 1024;
  const size_t k16 = (size_t)16 * K;

  for (int k0 = kb; k0 < ke; k0 += 32) {
    async_ld16(gA, lA);
    async_ld16(gA + k16, lA + 512);
    async_ld16(gB, lB);
    async_ld16(gB + k16, lB + 512);
    gA += 32; gB += 32;
    __syncthreads();   // compiler drains vmcnt(0) before barrier: LDS tiles valid

    bf16x8 af[4], bfr[4];
#pragma unroll
    for (int i = 0; i < 4; i++) {
      af[i]  = *(const bf16x8*)(sA + (wm + i * 16 + l16) * 32 + quad * 8);
      bfr[i] = *(const bf16x8*)(sB + (wn + i * 16 + l16) * 32 + quad * 8);
    }
#pragma unroll
    for (int mi = 0; mi < 4; mi++)
#pragma unroll
      for (int ni = 0; ni < 4; ni++)
        acc[mi][ni] = __builtin_amdgcn_mfma_f32_16x16x32_bf16(af[mi], bfr[ni], acc[mi][ni], 0, 0, 0);
    __syncthreads();   // protect LDS before next iteration's staging
  }

  const bool f32o = (EPI == E_BIAS_OUT) && (*f32out != 0);
  // epilogue: C/D layout col=lane&15, row=quad*4+reg (m89-verified)
#pragma unroll
  for (int mi = 0; mi < 4; mi++) {
#pragma unroll
    for (int ni = 0; ni < 4; ni++) {
      const int r0 = m0 + wm + mi * 16 + quad * 4;
      const int c  = n0 + wn + ni * 16 + l16;
      float bv = 0.f;
      if (EPI == E_BIAS_OUT || EPI == E_BIAS_RELU) bv = (float)bias[c];
      if (EPI == E_BIAS_RES_AT && kb == 0) bv = (float)bias[c];
#pragma unroll
      for (int r = 0; r < 4; r++) {
        float val = acc[mi][ni][r] + bv;
        if (EPI == E_BIAS_RELU) val = fmaxf(val, 0.f);
        const size_t idx = (size_t)(r0 + r) * N + c;
        if (EPI == E_BIAS_RES_AT) {
          atomicAdd(&resid[idx], val);   // split-K partial accumulate into fp32 residual
        } else if (EPI == E_BIAS_OUT) {
          if (f32o) ((float*)Cb)[idx] = val;
          else      ((bf16_t*)Cb)[idx] = (bf16_t)val;
        } else {
          ((bf16_t*)Cb)[idx] = (bf16_t)val;
        }
      }
    }
  }
}

__global__ __launch_bounds__(256) void k_gemm_qkv(const bf16_t* __restrict__ A,
                                                  const bf16_t* __restrict__ BT0,
                                                  const bf16_t* __restrict__ BT1,
                                                  const bf16_t* __restrict__ BT2,
                                                  bf16_t* __restrict__ o0,
                                                  bf16_t* __restrict__ o1,
                                                  bf16_t* __restrict__ o2,
                                                  int M, int N, int K) {
  const bf16_t* BT = (blockIdx.z == 0) ? BT0 : (blockIdx.z == 1) ? BT1 : BT2;
  bf16_t* o = (blockIdx.z == 0) ? o0 : (blockIdx.z == 1) ? o1 : o2;
  gemm_core<E_STORE>(A, BT, nullptr, o, nullptr, nullptr, M, N, K,
                     blockIdx.y * 128, blockIdx.x * 128, 0, K);
}
__global__ __launch_bounds__(256) void k_gemm_bias_relu(const bf16_t* __restrict__ A, const bf16_t* __restrict__ BT,
                                                        const bf16_t* __restrict__ bias, bf16_t* __restrict__ C,
                                                        int M, int N, int K) {
  gemm_core<E_BIAS_RELU>(A, BT, bias, C, nullptr, nullptr, M, N, K,
                         blockIdx.y * 128, blockIdx.x * 128, 0, K);
}
// split-K residual GEMM: gridDim.z K-chunks, fp32 atomic accumulate into resid
__global__ __launch_bounds__(256) void k_gemm_res_sk(const bf16_t* __restrict__ A, const bf16_t* __restrict__ BT,
                                                     const bf16_t* __restrict__ bias, float* __restrict__ resid,
                                                     int M, int N, int K) {
  const int kc = K / gridDim.z;
  const int kb = blockIdx.z * kc;
  gemm_core<E_BIAS_RES_AT>(A, BT, bias, nullptr, resid, nullptr, M, N, K,
                           blockIdx.y * 128, blockIdx.x * 128, kb, kb + kc);
}
// final GEMM: XCD-chunked swizzle, M-tiles fastest so each BT panel is read once into one XCD's L2
__global__ __launch_bounds__(256) void k_gemm_out(const bf16_t* __restrict__ A, const bf16_t* __restrict__ BT,
                                                  const bf16_t* __restrict__ bias, void* __restrict__ C,
                                                  const int* flag, int M, int N, int K) {
  const int nwg = gridDim.x * gridDim.y;
  int lid = blockIdx.y * gridDim.x + blockIdx.x;   // HW dispatch order (x fastest)
  if ((nwg & 7) == 0) {                            // bijective XCD chunking (4000%8==0)
    const int cpx = nwg >> 3;
    lid = (lid & 7) * cpx + (lid >> 3);
  }
  const int mt = lid % gridDim.y;                  // M fastest within chunk -> BT panel reuse
  const int nt = lid / gridDim.y;
  gemm_core<E_BIAS_OUT>(A, BT, bias, C, nullptr, flag, M, N, K,
                        mt * 128, nt * 128, 0, K);
}

// ======================= weight transpose into rotating slot: out[N,K] = in[K,N] =======================
__global__ __launch_bounds__(256) void k_t(const int* flag, const void* __restrict__ in, size_t eoff,
                                           bf16_t* __restrict__ out, int K, int N) {
  __shared__ bf16_t t[32][33];
  const bool f32 = (*flag != 0);
  const int n0 = blockIdx.x * 32, k0 = blockIdx.y * 32;
  const int tx = threadIdx.x, ty = threadIdx.y;  // (32,8)
#pragma unroll
  for (int i = 0; i < 4; i++)
    t[ty + 8 * i][tx] = (bf16_t)ldv(in, eoff + (size_t)(k0 + ty + 8 * i) * N + n0 + tx, f32);
  __syncthreads();
#pragma unroll
  for (int i = 0; i < 4; i++)
    out[(size_t)(n0 + ty + 8 * i) * K + k0 + tx] = t[tx][ty + 8 * i];
}

// q/k/v weights for one layer in one launch (z selects matrix, writes slot + z*DD)
__global__ __launch_bounds__(256) void k_t_qkv(const int* flag, const void* __restrict__ Wq,
                                               const void* __restrict__ Wk, const void* __restrict__ Wv,
                                               size_t eoff, bf16_t* __restrict__ out) {
  __shared__ bf16_t t[32][33];
  const bool f32 = (*flag != 0);
  const void* in = (blockIdx.z == 0) ? Wq : (blockIdx.z == 1) ? Wk : Wv;
  bf16_t* o = out + (size_t)blockIdx.z * DD;
  const int n0 = blockIdx.x * 32, k0 = blockIdx.y * 32;
  const int tx = threadIdx.x, ty = threadIdx.y;
#pragma unroll
  for (int i = 0; i < 4; i++)
    t[ty + 8 * i][tx] = (bf16_t)ldv(in, eoff + (size_t)(k0 + ty + 8 * i) * D_ + n0 + tx, f32);
  __syncthreads();
#pragma unroll
  for (int i = 0; i < 4; i++)
    o[(size_t)(n0 + ty + 8 * i) * D_ + k0 + tx] = t[tx][ty + 8 * i];
}

// ======================= V transpose: vt[b*768 + d][s] = v[b*1024 + s][d] =======================
__global__ __launch_bounds__(256) void k_vt(const bf16_t* __restrict__ v, bf16_t* __restrict__ vt) {
  __shared__ bf16_t t[32][33];
  const int b = blockIdx.z;
  const int n0 = blockIdx.x * 32, s0 = blockIdx.y * 32;
  const int tx = threadIdx.x, ty = threadIdx.y;  // (32,8)
#pragma unroll
  for (int i = 0; i < 4; i++)
    t[ty + 8 * i][tx] = v[(size_t)(b * S_ + s0 + ty + 8 * i) * D_ + n0 + tx];
  __syncthreads();
#pragma unroll
  for (int i = 0; i < 4; i++)
    vt[(size_t)(b * D_ + n0 + ty + 8 * i) * S_ + s0 + tx] = t[tx][ty + 8 * i];
}

// ======================= embedding (fp32 residual) =======================
__global__ __launch_bounds__(256) void k_embed(const int* flag, const int* __restrict__ cidx,
                                               const void* __restrict__ tok, const void* __restrict__ pos,
                                               float* __restrict__ x) {
  const bool f32 = (*flag != 0);
  const int t = blockIdx.x;
  const int id = cidx[t];
  const int s = t & (S_ - 1);
  for (int d = threadIdx.x; d < D_; d += 256)
    x[(size_t)t * D_ + d] = ldv(tok, (size_t)id * D_ + d, f32) + ldv(pos, (size_t)s * D_ + d, f32);
}

// ======================= layernorm: fp32 in -> bf16 out =======================
__global__ __launch_bounds__(256) void k_ln(const float* __restrict__ x, const bf16_t* __restrict__ g,
                                            const bf16_t* __restrict__ bta, bf16_t* __restrict__ out) {
  __shared__ float red[4];
  const int t = blockIdx.x, tid = threadIdx.x;
  const int wave = tid >> 6, lane = tid & 63;
  const float* xr = x + (size_t)t * D_;
  const float v0 = xr[tid], v1 = xr[tid + 256], v2 = xr[tid + 512];
  float s = wave_sum(v0 + v1 + v2);
  if (lane == 0) red[wave] = s;
  __syncthreads();
  const float mean = (red[0] + red[1] + red[2] + red[3]) * (1.f / 768.f);
  const float d0 = v0 - mean, d1 = v1 - mean, d2 = v2 - mean;
  float vs = wave_sum(d0 * d0 + d1 * d1 + d2 * d2);
  __syncthreads();
  if (lane == 0) red[wave] = vs;
  __syncthreads();
  const float inv = rsqrtf((red[0] + red[1] + red[2] + red[3]) * (1.f / 768.f) + 1e-5f);
  bf16_t* o = out + (size_t)t * D_;
  o[tid]       = (bf16_t)(d0 * inv * (float)g[tid]       + (float)bta[tid]);
  o[tid + 256] = (bf16_t)(d1 * inv * (float)g[tid + 256] + (float)bta[tid + 256]);
  o[tid + 512] = (bf16_t)(d2 * inv * (float)g[tid + 512] + (float)bta[tid + 512]);
}

// ======================= flash attention: 1 wave = 16 queries, MFMA QK^T and P@V ======================
__global__ __launch_bounds__(64) void k_fattn(const bf16_t* __restrict__ q,
                                              const bf16_t* __restrict__ k,
                                              const bf16_t* __restrict__ vt,
                                              bf16_t* __restrict__ ctx) {
  __shared__ bf16_t sP[16 * 40];
  const int lane = threadIdx.x;
  const int quad = lane >> 4, l16 = lane & 15;
  const int q0 = blockIdx.x << 4, h = blockIdx.y, b = blockIdx.z;
  const size_t hoff = (size_t)h * HD_;

  const bf16_t* qp = q + (size_t)(b * S_ + q0 + l16) * D_ + hoff + quad * 8;
  const bf16x8 af0 = *(const bf16x8*)qp;
  const bf16x8 af1 = *(const bf16x8*)(qp + 32);

  const f32x4 zero = {0.f, 0.f, 0.f, 0.f};
  f32x4 o_acc[4];
  float m_run[4], l_run[4];
#pragma unroll
  for (int ct = 0; ct < 4; ++ct) o_acc[ct] = zero;
#pragma unroll
  for (int r = 0; r < 4; ++r) { m_run[r] = -1e30f; l_run[r] = 0.f; }

  const int nt = ((q0 + 15) >> 5) + 1;
  const bf16_t* kbase = k + (size_t)(b * S_ + l16) * D_ + hoff + quad * 8;
  const size_t kst = (size_t)16 * D_;
  bf16x8 kf0 = *(const bf16x8*)(kbase);
  bf16x8 kf1 = *(const bf16x8*)(kbase + 32);
  bf16x8 kf2 = *(const bf16x8*)(kbase + kst);
  bf16x8 kf3 = *(const bf16x8*)(kbase + kst + 32);

  const bf16_t* vbase = vt + (size_t)(b * D_ + hoff + l16) * S_ + quad * 8;

  for (int kt = 0; kt < nt; ++kt) {
    const int k0 = kt << 5;
    const bf16_t* vrow = vbase + k0;
    const bf16x8 vb0 = *(const bf16x8*)(vrow);
    const bf16x8 vb1 = *(const bf16x8*)(vrow + 16 * S_);
    const bf16x8 vb2 = *(const bf16x8*)(vrow + 32 * S_);
    const bf16x8 vb3 = *(const bf16x8*)(vrow + 48 * S_);

    f32x4 d0 = zero, d1 = zero;
    d0 = __builtin_amdgcn_mfma_f32_16x16x32_bf16(af0, kf0, d0, 0, 0, 0);
    d0 = __builtin_amdgcn_mfma_f32_16x16x32_bf16(af1, kf1, d0, 0, 0, 0);
    d1 = __builtin_amdgcn_mfma_f32_16x16x32_bf16(af0, kf2, d1, 0, 0, 0);
    d1 = __builtin_amdgcn_mfma_f32_16x16x32_bf16(af1, kf3, d1, 0, 0, 0);

    if (kt + 1 < nt) {
      const bf16_t* kpn = kbase + (size_t)(k0 + 32) * D_;
      kf0 = *(const bf16x8*)(kpn);
      kf1 = *(const bf16x8*)(kpn + 32);
      kf2 = *(const bf16x8*)(kpn + kst);
      kf3 = *(const bf16x8*)(kpn + kst + 32);
    }

    const bool msk = (kt == nt - 1);
    float al[4];
#pragma unroll
    for (int r = 0; r < 4; ++r) {
      float s0 = d0[r] * 0.125f;
      float s1 = d1[r] * 0.125f;
      if (msk) {
        const int row = q0 + quad * 4 + r;
        if (k0 + l16      > row) s0 = -1e30f;
        if (k0 + 16 + l16 > row) s1 = -1e30f;
      }
      float mt = fmaxf(s0, s1);
      mt = fmaxf(mt, __shfl_xor(mt, 1));
      mt = fmaxf(mt, __shfl_xor(mt, 2));
      mt = fmaxf(mt, __shfl_xor(mt, 4));
      mt = fmaxf(mt, __shfl_xor(mt, 8));
      const float mn = fmaxf(m_run[r], mt);
      const float a  = __expf(m_run[r] - mn);
      m_run[r] = mn;
      const float p0 = __expf(s0 - mn);
      const float p1 = __expf(s1 - mn);
      float ps = p0 + p1;
      ps += __shfl_xor(ps, 1);
      ps += __shfl_xor(ps, 2);
      ps += __shfl_xor(ps, 4);
      ps += __shfl_xor(ps, 8);
      l_run[r] = l_run[r] * a + ps;
      al[r] = a;
      sP[(quad * 4 + r) * 40 + l16]      = (bf16_t)p0;
      sP[(quad * 4 + r) * 40 + 16 + l16] = (bf16_t)p1;
    }
#pragma unroll
    for (int ct = 0; ct < 4; ++ct) {
      o_acc[ct][0] *= al[0]; o_acc[ct][1] *= al[1];
      o_acc[ct][2] *= al[2]; o_acc[ct][3] *= al[3];
    }
    const bf16x8 pa = *(const bf16x8*)(sP + l16 * 40 + quad * 8);
    o_acc[0] = __builtin_amdgcn_mfma_f32_16x16x32_bf16(pa, vb0, o_acc[0], 0, 0, 0);
    o_acc[1] = __builtin_amdgcn_mfma_f32_16x16x32_bf16(pa, vb1, o_acc[1], 0, 0, 0);
    o_acc[2] = __builtin_amdgcn_mfma_f32_16x16x32_bf16(pa, vb2, o_acc[2], 0, 0, 0);
    o_acc[3] = __builtin_amdgcn_mfma_f32_16x16x32_bf16(pa, vb3, o_acc[3], 0, 0, 0);
  }

  float inv[4];
#pragma unroll
  for (int r = 0; r < 4; ++r) inv[r] = 1.f / l_run[r];
  bf16_t* cp = ctx + (size_t)(b * S_ + q0 + quad * 4) * D_ + hoff + l16;
#pragma unroll
  for (int ct = 0; ct < 4; ++ct)
#pragma unroll
    for (int r = 0; r < 4; ++r)
      cp[(size_t)r * D_ + ct * 16] = (bf16_t)(o_acc[ct][r] * inv[r]);
}

// ======================= host =======================
extern "C" void kernel_launch(void* const* d_in, const int* in_sizes, int n_in,
                              void* d_out, int out_size, void* d_ws, size_t ws_size,
                              hipStream_t stream) {
  (void)in_sizes; (void)n_in; (void)out_size; (void)ws_size;
  const int* cidx = (const int*)d_in[0];
  const void* tok  = d_in[1];
  const void* pos  = d_in[2];
  const void* Wq   = d_in[3];
  const void* Wk   = d_in[4];
  const void* Wv   = d_in[5];
  const void* Wo   = d_in[6];
  const void* bo   = d_in[7];
  const void* ln1g = d_in[8];
  const void* ln1b = d_in[9];
  const void* W1   = d_in[10];
  const void* b1   = d_in[11];
  const void* W2   = d_in[12];
  const void* b2   = d_in[13];
  const void* ln2g = d_in[14];
  const void* ln2b = d_in[15];
  const void* lnfg = d_in[16];
  const void* lnfb = d_in[17];
  const void* Wout = d_in[18];
  const void* bout = d_in[19];

  // ---- workspace carve ----
  char* p = (char*)d_ws;
  int*    flag  = (int*)p;
  bf16_t* canon = (bf16_t*)(p + 256);
  char*   q     = p + 256 + 163840;
  float*  x     = (float*)q;  q += (size_t)NTOK * D_ * 4;       // 6.29 MB
  bf16_t* h     = (bf16_t*)q; q += (size_t)NTOK * D_ * 2;       // 3.15 MB
  bf16_t* qb    = (bf16_t*)q; q += (size_t)NTOK * D_ * 2;
  bf16_t* kbuf  = (bf16_t*)q; q += (size_t)NTOK * D_ * 2;
  bf16_t* vbuf  = (bf16_t*)q; q += (size_t)NTOK * D_ * 2;
  bf16_t* cbuf  = (bf16_t*)q; q += (size_t)NTOK * D_ * 2;
  bf16_t* mid   = (bf16_t*)q; q += (size_t)NTOK * 4 * D_ * 2;   // 12.6 MB
  bf16_t* slot  = (bf16_t*)q; q += (size_t)D_ * V_ * 2;         // 49.2 MB
  bf16_t* vt = mid;   // vt aliases mid (disjoint lifetimes on the serial stream)

  bf16_t* c_bo  = canon + 0;
  bf16_t* c_b1  = canon + 4608;
  bf16_t* c_b2  = canon + 23040;
  bf16_t* c_l1g = canon + 27648;
  bf16_t* c_l1b = canon + 32256;
  bf16_t* c_l2g = canon + 36864;
  bf16_t* c_l2b = canon + 41472;
  bf16_t* c_lfg = canon + 46080;
  bf16_t* c_lfb = canon + 46848;
  bf16_t* c_bout= canon + 47616;

  const dim3 tb(32, 8);
  k_sniff<<<1, 64, 0, stream>>>(tok, flag);
  k_cvt_bias<<<dim3(125, 10), 256, 0, stream>>>(flag, canon, bo, b1, b2, ln1g, ln1b,
                                                ln2g, ln2b, lnfg, lnfb, bout);
  k_embed<<<NTOK, 256, 0, stream>>>(flag, cidx, tok, pos, x);

  const dim3 gF(4 * D_ / 128, NTOK / 128);        // FFN1: N=3072
  const dim3 gSK2(D_ / 128, NTOK / 128, 2);       // attn-proj split-K x2 (192 blocks)
  const dim3 gSK4(D_ / 128, NTOK / 128, 4);       // FFN2 split-K x4 (384 blocks)
  for (int l = 0; l < L_; ++l) {
    const size_t wo = (size_t)l * DD;
    const size_t wf = (size_t)l * D4D;
    k_ln<<<NTOK, 256, 0, stream>>>(x, c_l1g + l * D_, c_l1b + l * D_, h);
    k_t_qkv<<<dim3(24, 24, 3), tb, 0, stream>>>(flag, Wq, Wk, Wv, wo, slot);
    k_gemm_qkv<<<dim3(D_ / 128, NTOK / 128, 3), 256, 0, stream>>>(
        h, slot, slot + DD, slot + 2 * DD, qb, kbuf, vbuf, NTOK, D_, D_);
    k_vt<<<dim3(24, 32, 2), tb, 0, stream>>>(vbuf, vt);
    k_fattn<<<dim3(S_ / 16, H_, B_), 64, 0, stream>>>(qb, kbuf, vt, cbuf);
    k_t<<<dim3(24, 24), tb, 0, stream>>>(flag, Wo, wo, slot, D_, D_);
    k_gemm_res_sk<<<gSK2, 256, 0, stream>>>(cbuf, slot, c_bo + l * D_, x, NTOK, D_, D_);
    k_ln<<<NTOK, 256, 0, stream>>>(x, c_l2g + l * D_, c_l2b + l * D_, h);
    k_t<<<dim3(96, 24), tb, 0, stream>>>(flag, W1, wf, slot, D_, 4 * D_);
    k_gemm_bias_relu<<<gF, 256, 0, stream>>>(h, slot, c_b1 + l * 4 * D_, mid, NTOK, 4 * D_, D_);
    k_t<<<dim3(24, 96), tb, 0, stream>>>(flag, W2, wf, slot, 4 * D_, D_);
    k_gemm_res_sk<<<gSK4, 256, 0, stream>>>(mid, slot, c_b2 + l * D_, x, NTOK, D_, 4 * D_);
  }
  k_ln<<<NTOK, 256, 0, stream>>>(x, c_lfg, c_lfb, h);
  k_t<<<dim3(1000, 24), tb, 0, stream>>>(flag, Wout, 0, slot, D_, V_);
  k_gemm_out<<<dim3(V_ / 128, NTOK / 128), 256, 0, stream>>>(h, slot, c_bout, d_out, flag,
                                                             NTOK, V_, D_);
}